// Round 4
// baseline (67698.602 us; speedup 1.0000x reference)
//
#include <hip/hip_runtime.h>
#include <hip/hip_bf16.h>
#include <stdint.h>

// ---------------- types ----------------
using bfrag_t = __attribute__((ext_vector_type(8))) short;  // 8 bf16 (4 VGPRs)
using f32x4   = __attribute__((ext_vector_type(4))) float;  // MFMA acc

#define HID  512
#define H3   256
#define RB   64       // rows per SLAB (two slabs per block = 128 rows/block)
#define NTH  512      // 8 waves
#define KSC  2.885390081777927f   // 2*log2(e): tanh(x) = 1 - 2/(exp2(KSC*x)+1)

static __device__ __forceinline__ uint32_t bf16_rne(float f) {
    uint32_t u = __float_as_uint(f);
    return (u + 0x7fffu + ((u >> 16) & 1u)) >> 16;
}
static __device__ __forceinline__ uint32_t pk_bf16(float a, float b) {
    union { __hip_bfloat162 h; uint32_t u; } c;
    c.h = __float22bfloat162_rn(make_float2(a, b));   // v_cvt_pk_bf16_f32
    return c.u;
}
static __device__ __forceinline__ float fast_exp2(float x) {
#if __has_builtin(__builtin_amdgcn_exp2f)
    return __builtin_amdgcn_exp2f(x);
#else
    return exp2f(x);
#endif
}
static __device__ __forceinline__ float fast_rcp(float x) {
#if __has_builtin(__builtin_amdgcn_rcpf)
    return __builtin_amdgcn_rcpf(x);
#else
    return 1.0f / x;
#endif
}
// input PRE-SCALED by KSC
static __device__ __forceinline__ float ftanh_s(float xs) {
    float e = fast_exp2(xs);
    return 1.0f - 2.0f * fast_rcp(e + 1.0f);
}
static __device__ __forceinline__ bfrag_t frag_of(uint4 v) {
    union { uint4 u; bfrag_t f; } c; c.u = v; return c.f;
}

// ---------------- prep (unchanged from R3): W2^T/W3^T scaled to MFMA A-frag order ----
__global__ void prep_weights(const float* __restrict__ W1, const float* __restrict__ b1,
                             const float* __restrict__ W2, const float* __restrict__ b2,
                             const float* __restrict__ W3, const float* __restrict__ b3,
                             uint4* __restrict__ o2, uint4* __restrict__ o3,
                             float* __restrict__ w1p, float* __restrict__ b2s,
                             float* __restrict__ b3s)
{
    int id = blockIdx.x * 256 + threadIdx.x;
    if (id < 32768) {                       // W2: 32 mt * 16 kt * 64 lanes
        int l = id & 63, kt = (id >> 6) & 15, mt = id >> 10;
        int m = mt * 16 + (l & 15), k0 = kt * 32 + (l >> 4) * 8;
        uint32_t p[4];
        #pragma unroll
        for (int jj = 0; jj < 4; ++jj) {
            float v0 = KSC * W2[(k0 + jj * 2    ) * 512 + m];
            float v1 = KSC * W2[(k0 + jj * 2 + 1) * 512 + m];
            p[jj] = bf16_rne(v0) | (bf16_rne(v1) << 16);
        }
        o2[id] = make_uint4(p[0], p[1], p[2], p[3]);
    } else if (id < 49152) {                // W3: 16 mt * 16 kt * 64 lanes
        int id2 = id - 32768;
        int l = id2 & 63, kt = (id2 >> 6) & 15, mt = id2 >> 10;
        int m = mt * 16 + (l & 15), k0 = kt * 32 + (l >> 4) * 8;
        uint32_t p[4];
        #pragma unroll
        for (int jj = 0; jj < 4; ++jj) {
            float v0 = KSC * W3[(k0 + jj * 2    ) * 256 + m];
            float v1 = KSC * W3[(k0 + jj * 2 + 1) * 256 + m];
            p[jj] = bf16_rne(v0) | (bf16_rne(v1) << 16);
        }
        o3[id2] = make_uint4(p[0], p[1], p[2], p[3]);
    } else if (id < 49152 + 1536) {         // W1 pack: 64 chunks x 24 floats
        int t = id - 49152;
        int ck = t / 24, j = t % 24;
        int f = ck * 8 + (j & 7);
        float v = (j < 8) ? W1[f] : (j < 16) ? W1[512 + f] : b1[f];
        w1p[t] = KSC * v;
    } else if (id < 49152 + 1536 + 512) {
        int i = id - 49152 - 1536; b2s[i] = KSC * b2[i];
    } else if (id < 49152 + 1536 + 512 + 256) {
        int i = id - 49152 - 1536 - 512; b3s[i] = KSC * b3[i];
    }
}

// ---------------- main kernel: 2-slab stage-paired pipeline ----------------
// Per slab, h stored transposed in LDS chunks: h[ck*64 + r] = 8 bf16 features
// [ck*8..ck*8+7] of local row r.
struct SmemT {
    uint4  hA[64 * RB];      // 64 KB  slab A hidden buffer
    uint4  hB[64 * RB];      // 64 KB  slab B hidden buffer
    float  b2[HID];          // scaled
    float  b3[H3];           // scaled
    float  y [128][2];
    float  z [128][2];
    float  ya[128][2];
    float  part[8][RB][2];   // layer4 partials (one slab at a time)
};

// ---- stage bodies (forceinline, operate on one slab) ----
static __device__ __forceinline__ void s1_stage(uint4* __restrict__ h,
                                                const float* __restrict__ zrow,
                                                const float* __restrict__ w1w,
                                                int l, int wu)
{
    float z0 = zrow[2 * l], z1 = zrow[2 * l + 1];
    #pragma unroll
    for (int i = 0; i < 8; ++i) {
        const float* P = w1w + i * 24;     // uniform -> s_load
        int ck = wu * 8 + i;
        float x[8];
        #pragma unroll
        for (int jj = 0; jj < 8; ++jj)
            x[jj] = ftanh_s(fmaf(z0, P[jj], fmaf(z1, P[8 + jj], P[16 + jj])));
        h[ck * RB + l] = make_uint4(pk_bf16(x[0], x[1]), pk_bf16(x[2], x[3]),
                                    pk_bf16(x[4], x[5]), pk_bf16(x[6], x[7]));
    }
}

static __device__ __forceinline__ void s2_mfma(const uint4* __restrict__ h,
                                               const uint4* __restrict__ w2A,
                                               const float* __restrict__ b2,
                                               f32x4 (&acc)[4][4],
                                               int l, int w, int q, int rr)
{
    #pragma unroll
    for (int mt = 0; mt < 4; ++mt) {
        int mb = (w * 4 + mt) * 16 + q * 4;
        float4 bi = *(const float4*)&b2[mb];
        #pragma unroll
        for (int nt = 0; nt < 4; ++nt) acc[mt][nt] = (f32x4){bi.x, bi.y, bi.z, bi.w};
    }
    uint4 aC[4], aN[4];
    #pragma unroll
    for (int mt = 0; mt < 4; ++mt) aC[mt] = w2A[((w * 4 + mt) * 16) * 64 + l];
    for (int kt = 0; kt < 16; ++kt) {
        uint4 bF[4];
        #pragma unroll
        for (int nt = 0; nt < 4; ++nt)
            bF[nt] = h[(kt * 4 + q) * RB + nt * 16 + rr];
        if (kt < 15) {
            #pragma unroll
            for (int mt = 0; mt < 4; ++mt)
                aN[mt] = w2A[(((w * 4 + mt) * 16) + kt + 1) * 64 + l];
        }
        #pragma unroll
        for (int mt = 0; mt < 4; ++mt)
            #pragma unroll
            for (int nt = 0; nt < 4; ++nt)
                acc[mt][nt] = __builtin_amdgcn_mfma_f32_16x16x32_bf16(
                    frag_of(aC[mt]), frag_of(bF[nt]), acc[mt][nt], 0, 0, 0);
        #pragma unroll
        for (int mt = 0; mt < 4; ++mt) aC[mt] = aN[mt];
    }
}

static __device__ __forceinline__ void s2_epi(uint4* __restrict__ h,
                                              f32x4 (&acc)[4][4],
                                              int w, int q, int rr)
{
    #pragma unroll
    for (int mt = 0; mt < 4; ++mt) {
        int mb = (w * 4 + mt) * 16 + q * 4;
        int ck = mb >> 3, hi = (mb >> 2) & 1;
        #pragma unroll
        for (int nt = 0; nt < 4; ++nt) {
            int n = nt * 16 + rr;
            f32x4 c = acc[mt][nt];
            uint32_t u0 = pk_bf16(ftanh_s(c[0]), ftanh_s(c[1]));
            uint32_t u1 = pk_bf16(ftanh_s(c[2]), ftanh_s(c[3]));
            ((uint2*)h)[((ck * RB + n) << 1) | hi] = make_uint2(u0, u1);
        }
    }
}

static __device__ __forceinline__ void s3_mfma(const uint4* __restrict__ h,
                                               const uint4* __restrict__ w3A,
                                               const float* __restrict__ b3,
                                               f32x4 (&acc)[2][4],
                                               int l, int w, int q, int rr)
{
    #pragma unroll
    for (int mt = 0; mt < 2; ++mt) {
        int mb = (w * 2 + mt) * 16 + q * 4;
        float4 bi = *(const float4*)&b3[mb];
        #pragma unroll
        for (int nt = 0; nt < 4; ++nt) acc[mt][nt] = (f32x4){bi.x, bi.y, bi.z, bi.w};
    }
    uint4 aC[2], aN[2];
    #pragma unroll
    for (int mt = 0; mt < 2; ++mt) aC[mt] = w3A[((w * 2 + mt) * 16) * 64 + l];
    for (int kt = 0; kt < 16; ++kt) {
        uint4 bF[4];
        #pragma unroll
        for (int nt = 0; nt < 4; ++nt)
            bF[nt] = h[(kt * 4 + q) * RB + nt * 16 + rr];
        if (kt < 15) {
            #pragma unroll
            for (int mt = 0; mt < 2; ++mt)
                aN[mt] = w3A[(((w * 2 + mt) * 16) + kt + 1) * 64 + l];
        }
        #pragma unroll
        for (int mt = 0; mt < 2; ++mt)
            #pragma unroll
            for (int nt = 0; nt < 4; ++nt)
                acc[mt][nt] = __builtin_amdgcn_mfma_f32_16x16x32_bf16(
                    frag_of(aC[mt]), frag_of(bF[nt]), acc[mt][nt], 0, 0, 0);
        #pragma unroll
        for (int mt = 0; mt < 2; ++mt) aC[mt] = aN[mt];
    }
}

static __device__ __forceinline__ void s3_epi(uint4* __restrict__ h,
                                              f32x4 (&acc)[2][4],
                                              int w, int q, int rr)
{
    #pragma unroll
    for (int mt = 0; mt < 2; ++mt) {
        int mb = (w * 2 + mt) * 16 + q * 4;   // 0..255 -> ck 0..31
        int ck = mb >> 3, hi = (mb >> 2) & 1;
        #pragma unroll
        for (int nt = 0; nt < 4; ++nt) {
            int n = nt * 16 + rr;
            f32x4 c = acc[mt][nt];
            uint32_t u0 = pk_bf16(ftanh_s(c[0]), ftanh_s(c[1]));
            uint32_t u1 = pk_bf16(ftanh_s(c[2]), ftanh_s(c[3]));
            ((uint2*)h)[((ck * RB + n) << 1) | hi] = make_uint2(u0, u1);
        }
    }
}

static __device__ __forceinline__ void s4_part(const uint4* __restrict__ h,
                                               float* __restrict__ part,
                                               const float* __restrict__ W4g,
                                               int tid)
{
    int r  = tid & 63;
    int qq = __builtin_amdgcn_readfirstlane(tid >> 6);   // 0..7 uniform (wave id)
    float a0 = 0.f, a1 = 0.f;
    #pragma unroll
    for (int j = 0; j < 4; ++j) {
        int ck = qq * 4 + j;
        uint4 hv = h[ck * RB + r];
        const uint32_t* pu = (const uint32_t*)&hv;
        #pragma unroll
        for (int jj = 0; jj < 4; ++jj) {
            uint32_t uu = pu[jj];
            float h0 = __uint_as_float(uu << 16);
            float h1 = __uint_as_float(uu & 0xffff0000u);
            int f = ck * 8 + jj * 2;                     // uniform
            a0 = fmaf(h0, W4g[f * 2],     fmaf(h1, W4g[f * 2 + 2], a0));
            a1 = fmaf(h0, W4g[f * 2 + 1], fmaf(h1, W4g[f * 2 + 3], a1));
        }
    }
    part[(qq * RB + r) * 2    ] = a0;
    part[(qq * RB + r) * 2 + 1] = a1;
}

static __device__ __forceinline__ void s4_fin(float* __restrict__ yS, float* __restrict__ zS,
                                              float* __restrict__ yaS,
                                              const float* __restrict__ part,
                                              const float* __restrict__ tp,
                                              const float* __restrict__ b4g,
                                              float* __restrict__ out,
                                              int g, int Bn, int rowg, int tid)
{
    if (tid < RB) {
        int r = tid;
        float k0 = b4g[0], k1 = b4g[1];
        #pragma unroll
        for (int qq = 0; qq < 8; ++qq) {
            k0 += part[(qq * RB + r) * 2];
            k1 += part[(qq * RB + r) * 2 + 1];
        }
        int st = g >> 2, e = g & 3;
        float dt = tp[st + 1] - tp[st];
        float wg = (e == 0 || e == 3) ? dt * (1.f / 6.f) : dt * (1.f / 3.f);
        float ya0 = yaS[2 * r] + wg * k0, ya1 = yaS[2 * r + 1] + wg * k1;
        yaS[2 * r] = ya0; yaS[2 * r + 1] = ya1;
        if (e < 3) {
            float aa = (e == 2) ? dt : dt * 0.5f;
            zS[2 * r] = yS[2 * r] + aa * k0;
            zS[2 * r + 1] = yS[2 * r + 1] + aa * k1;
        } else {
            yS[2 * r] = ya0; yS[2 * r + 1] = ya1;
            zS[2 * r] = ya0; zS[2 * r + 1] = ya1;
            ((float2*)out)[(size_t)(st + 1) * Bn + rowg + r] = make_float2(ya0, ya1);
        }
    }
}

__global__ __launch_bounds__(NTH, 2) void node_kernel(
    const float* __restrict__ y0, const float* __restrict__ tp,
    const float* __restrict__ W4g, const float* __restrict__ b4g,
    const uint4* __restrict__ w2A, const uint4* __restrict__ w3A,
    const float* __restrict__ w1p, const float* __restrict__ b2s,
    const float* __restrict__ b3s,
    float* __restrict__ out, int Bn, int T)
{
    __shared__ SmemT s;
    const int tid = threadIdx.x;
    const int l   = tid & 63;
    const int w   = tid >> 6;
    const int wu  = __builtin_amdgcn_readfirstlane(w);
    const int q   = l >> 4, rr = l & 15;
    const int b0  = blockIdx.x * 128;

    for (int i = tid; i < HID; i += NTH) s.b2[i] = b2s[i];
    for (int i = tid; i < H3;  i += NTH) s.b3[i] = b3s[i];
    if (tid < 128) {
        float2 v = ((const float2*)y0)[b0 + tid];
        s.y[tid][0] = v.x; s.y[tid][1] = v.y;
        s.z[tid][0] = v.x; s.z[tid][1] = v.y;
        s.ya[tid][0] = v.x; s.ya[tid][1] = v.y;
        ((float2*)out)[b0 + tid] = v;          // trajectory[0] = y0
    }
    __syncthreads();

    const float* w1w = w1p + wu * 192;
    float* part = &s.part[0][0][0];
    const int E = (T - 1) * 4;                 // total evals per slab

    // Pipeline: slab B lags slab A by 2 stages.
    // iter ea: T1[B.L3m | A.L1]/[B.L3e]  T2[A.L2m | B.L4p]/[A.L2e | B.fin(ea-1)]
    //          T3[A.L3m | B.L1]/[A.L3e]  T4[B.L2m | A.L4p]/[B.L2e | A.fin(ea)]
    for (int ea = 0; ea <= E; ++ea) {
        const bool doA = (ea < E), doB = (ea > 0);
        const int gB = ea - 1;

        // ---------------- tick 1 ----------------
        {
            f32x4 c3[2][4];
            if (doB) s3_mfma(s.hB, w3A, s.b3, c3, l, w, q, rr);
            if (doA) s1_stage(s.hA, &s.z[0][0], w1w, l, wu);
            __syncthreads();
            if (doB) s3_epi(s.hB, c3, w, q, rr);
            __syncthreads();
        }

        // ---------------- tick 2 ----------------
        {
            f32x4 c2[4][4];
            if (doA) s2_mfma(s.hA, w2A, s.b2, c2, l, w, q, rr);
            if (doB) s4_part(s.hB, part, W4g, tid);
            __syncthreads();
            if (doA) s2_epi(s.hA, c2, w, q, rr);
            if (doB) s4_fin(&s.y[64][0], &s.z[64][0], &s.ya[64][0], part,
                            tp, b4g, out, gB, Bn, b0 + 64, tid);
            __syncthreads();
        }

        // ---------------- tick 3 ----------------
        {
            f32x4 c3[2][4];
            if (doA) s3_mfma(s.hA, w3A, s.b3, c3, l, w, q, rr);
            if (doA) s1_stage(s.hB, &s.z[64][0], w1w, l, wu);
            __syncthreads();
            if (doA) s3_epi(s.hA, c3, w, q, rr);
            __syncthreads();
        }

        // ---------------- tick 4 ----------------
        {
            f32x4 c2[4][4];
            if (doA) s2_mfma(s.hB, w2A, s.b2, c2, l, w, q, rr);
            if (doA) s4_part(s.hA, part, W4g, tid);
            __syncthreads();
            if (doA) s2_epi(s.hB, c2, w, q, rr);
            if (doA) s4_fin(&s.y[0][0], &s.z[0][0], &s.ya[0][0], part,
                            tp, b4g, out, ea, Bn, b0, tid);
            __syncthreads();
        }
    }
}

extern "C" void kernel_launch(void* const* d_in, const int* in_sizes, int n_in,
                              void* d_out, int out_size, void* d_ws, size_t ws_size,
                              hipStream_t stream)
{
    const float* y0 = (const float*)d_in[0];
    const float* tp = (const float*)d_in[1];
    const float* W1 = (const float*)d_in[2];
    const float* b1 = (const float*)d_in[3];
    const float* W2 = (const float*)d_in[4];
    const float* b2 = (const float*)d_in[5];
    const float* W3 = (const float*)d_in[6];
    const float* b3 = (const float*)d_in[7];
    const float* W4 = (const float*)d_in[8];
    const float* b4 = (const float*)d_in[9];
    float* out = (float*)d_out;

    const int Bn = in_sizes[0] / 2;
    const int T  = in_sizes[1];

    uint4* w2A = (uint4*)d_ws;            // 32768 uint4 = 512 KB
    uint4* w3A = w2A + 32768;             // 16384 uint4 = 256 KB
    float* w1p = (float*)(w3A + 16384);   // 1536 floats (scaled W1 pack)
    float* b2s = w1p + 1536;              // 512 floats
    float* b3s = b2s + 512;               // 256 floats

    prep_weights<<<201, 256, 0, stream>>>(W1, b1, W2, b2, W3, b3,
                                          w2A, w3A, w1p, b2s, b3s);
    node_kernel<<<Bn / 128, NTH, 0, stream>>>(y0, tp, W4, b4,
                                              w2A, w3A, w1p, b2s, b3s, out, Bn, T);
}